// Round 8
// baseline (734.376 us; speedup 1.0000x reference)
//
#include <hip/hip_runtime.h>
#include <hip/hip_bf16.h>
#include <stdint.h>

#define BATCH 512
#define PIX   196
#define EDIM  2048
#define DDIM  512
#define ADIM  512
#define MROWS (BATCH*PIX)   // 100352 = 392*256

#define BM 256
#define BN 256
#define BK 64
#define NT (EDIM/BK)        // 32

typedef __attribute__((ext_vector_type(8))) short bf16x8;
typedef __attribute__((ext_vector_type(8))) float f32x8;
typedef __attribute__((ext_vector_type(8))) __bf16 bf16v8;
typedef __attribute__((ext_vector_type(4))) float f32x4;

#define GLL16(g, lptr) __builtin_amdgcn_global_load_lds( \
    (const __attribute__((address_space(1))) void*)(g),  \
    (__attribute__((address_space(3))) void*)(lptr), 16, 0, 0)

static __device__ __forceinline__ unsigned short f2bf(float f) {
  union { float f; uint32_t u; } v; v.f = f;
  uint32_t u = v.u;
  return (unsigned short)((u + 0x7FFFu + ((u >> 16) & 1u)) >> 16);  // RNE
}

// fp32x8 -> bf16x8 via compiler-selected v_cvt_pk_bf16_f32 (RNE)
static __device__ __forceinline__ bf16x8 cvt8(float4 a, float4 b) {
  f32x8 v = {a.x, a.y, a.z, a.w, b.x, b.y, b.z, b.w};
  bf16v8 c = __builtin_convertvector(v, bf16v8);
  bf16x8 r;
  __builtin_memcpy(&r, &c, 16);
  return r;
}

// ---------------- K0a: W_enc [2048][512] f32 -> Bt [512][2048] bf16 ----------
__global__ void k_transpose_wenc(const float* __restrict__ W,
                                 unsigned short* __restrict__ Bt) {
  __shared__ float tile[32][33];
  const int kt = blockIdx.x;            // 64 tiles over K
  const int nt = blockIdx.y;            // 16 tiles over N
  const int tx = threadIdx.x, ty = threadIdx.y;   // 32 x 8
#pragma unroll
  for (int j = 0; j < 4; j++)
    tile[ty + 8*j][tx] = W[(size_t)(kt*32 + ty + 8*j)*ADIM + nt*32 + tx];
  __syncthreads();
#pragma unroll
  for (int j = 0; j < 4; j++)
    Bt[(size_t)(nt*32 + ty + 8*j)*EDIM + kt*32 + tx] = f2bf(tile[tx][ty + 8*j]);
}

// ---------------- K0b: att2 = hidden @ W_dec + b_dec ------------------------
__global__ void k_att2(const float* __restrict__ H, const float* __restrict__ Wd,
                       const float* __restrict__ bd, float* __restrict__ att2) {
  __shared__ float h[DDIM];
  const int b = blockIdx.x;
  const int t = threadIdx.x;            // 256
  h[t]       = H[(size_t)b*DDIM + t];
  h[t + 256] = H[(size_t)b*DDIM + t + 256];
  __syncthreads();
  float a0 = 0.f, a1 = 0.f;
#pragma unroll 8
  for (int k = 0; k < DDIM; k++) {
    const float hv = h[k];
    a0 += hv * Wd[(size_t)k*ADIM + t];
    a1 += hv * Wd[(size_t)k*ADIM + t + 256];
  }
  att2[(size_t)b*ADIM + t]       = a0 + bd[t];
  att2[(size_t)b*ADIM + t + 256] = a1 + bd[t + 256];
}

// ---------------- K1: fused att1-GEMM + tanh + scores(partial) --------------
// 256x256 tile, BK=64, 512 threads (8 waves 2Mx4N, 128x64 out per wave).
// 8-phase schedule (4 phases/K-tile): each phase = {ds_read subtile ||
// stage ops -> barrier -> lgkmcnt(0)+sched_barrier -> setprio(1) -> 16 MFMA
// -> setprio(0) -> barrier}. Counted vmcnt; B-GLL drain only at P3 (L2-hot).
__global__ __launch_bounds__(512) void k_gemm_scores(
    const float* __restrict__ enc,          // [M][2048] f32
    const unsigned short* __restrict__ Bt,  // [512][2048] bf16
    const float* __restrict__ b_enc,        // [512]
    const float* __restrict__ att2,         // [B][512]
    const float* __restrict__ W_full,       // [512]
    float* __restrict__ scores)             // [M] (pre-zeroed, atomicAdd)
{
  __shared__ __align__(16) char ldsA[2*32768];   // [buf][256 rows][64 bf16]
  __shared__ __align__(16) char ldsB[2*32768];
  __shared__ float sc[BM];

  const int t   = threadIdx.x;          // 0..511
  const int l   = t & 63;
  const int wid = t >> 6;               // 0..7
  const int wr  = wid >> 2;             // 0..1 (M)
  const int wc  = wid & 3;              // 0..3 (N)

  // XCD swizzle (nwg=784=8*98), n-minor: the 2 N-tiles of one M-tile run
  // consecutively on one XCD -> A-tile (2MB) L2-resident across both.
  const int orig = blockIdx.x;
  const int tile = (orig & 7) * 98 + (orig >> 3);
  const int bm0 = (tile >> 1) * BM;
  const int bn0 = (tile & 1) * BN;

  if (t < BM) sc[t] = 0.f;

  // ---- A staging: thread -> row t>>1, 32 cols at (t&1)*32 ----
  const int arow = t >> 1;
  const int ah   = t & 1;
  const float* srcA = enc + (size_t)(bm0 + arow) * EDIM + ah * 32;
  int wA[4];
#pragma unroll
  for (int j = 0; j < 4; j++)
    wA[j] = arow*128 + (((ah*4 + j) ^ (arow & 7)) * 16);

  // ---- B staging: GLL linear dest (byte t*16 + j*8192); source chunk
  //      pre-XOR'd so LDS (row,chunk) holds global chunk (chunk^row&7) ----
  const unsigned short* srcB[4];
#pragma unroll
  for (int j = 0; j < 4; j++) {
    const int row = (t >> 3) + j*64;
    srcB[j] = Bt + (size_t)(bn0 + row) * EDIM + ((t & 7) ^ (row & 7)) * 8;
  }
  const int dstB = wid * 1024;          // + j*8192 ; lane*16 implicit

  // ---- fragment read addresses ----
  const int l15 = l & 15, hi = l >> 4;
  const int sw  = l15 & 7;              // row&7 for all frag rows
  const int c0  = (hi ^ sw) * 16;       // ks=0 chunk byte
  const int c1  = ((4 + hi) ^ sw) * 16; // ks=1 chunk byte
  const int baseA = (wr*128 + l15) * 128;
  const int baseB = (wc*64  + l15) * 128;

  float4 ar[8];
  bf16x8 af[4], bfr[4];
  f32x4 acc[8][4] = {};

#define A_ISSUE(KT) do {                                         \
    const float* _s = srcA + (size_t)(KT) * BK;                  \
    _Pragma("unroll")                                            \
    for (int j = 0; j < 8; j++) ar[j] = ((const float4*)_s)[j];  \
  } while (0)

#define B_GLLJ(NXT, KT, J) \
    GLL16(srcB[J] + (size_t)(KT) * BK, ldsB + (NXT)*32768 + dstB + (J)*8192)

#define A_WRITE(NXT) do {                                        \
    _Pragma("unroll")                                            \
    for (int j = 0; j < 4; j++) {                                \
      bf16x8 w = cvt8(ar[2*j], ar[2*j + 1]);                     \
      *(bf16x8*)(ldsA + (NXT)*32768 + wA[j]) = w;                \
    }                                                            \
  } while (0)

#define DSREAD_B(CUR, CKS) do {                                  \
    _Pragma("unroll")                                            \
    for (int ni = 0; ni < 4; ni++)                               \
      bfr[ni] = *(const bf16x8*)(ldsB + (CUR)*32768 + baseB + ni*2048 + (CKS)); \
  } while (0)

#define DSREAD_A(CUR, CKS, MOFF) do {                            \
    _Pragma("unroll")                                            \
    for (int mi = 0; mi < 4; mi++)                               \
      af[mi] = *(const bf16x8*)(ldsA + (CUR)*32768 + baseA + (mi+(MOFF))*2048 + (CKS)); \
  } while (0)

#define BARLG()                                                  \
    __builtin_amdgcn_s_barrier();                                \
    asm volatile("s_waitcnt lgkmcnt(0)" ::: "memory");           \
    __builtin_amdgcn_sched_barrier(0);                           \
    __builtin_amdgcn_s_setprio(1)

#define ENDBAR()                                                 \
    __builtin_amdgcn_s_setprio(0);                               \
    __builtin_amdgcn_s_barrier()

#define MF16(MOFF) do {                                          \
    _Pragma("unroll")                                            \
    for (int mi = 0; mi < 4; mi++)                               \
      _Pragma("unroll")                                          \
      for (int ni = 0; ni < 4; ni++)                             \
        acc[mi+(MOFF)][ni] = __builtin_amdgcn_mfma_f32_16x16x32_bf16( \
            af[mi], bfr[ni], acc[mi+(MOFF)][ni], 0, 0, 0);       \
  } while (0)

  // One K-tile = 4 phases. CUR computed, NXT staged (tile KT+1).
#define TILE(KT, CUR, NXT) do {                                  \
    /* P0 */                                                     \
    A_ISSUE((KT)+1);                                             \
    DSREAD_B(CUR, c0); DSREAD_A(CUR, c0, 0);                     \
    BARLG(); MF16(0); ENDBAR();                                  \
    /* P1 */                                                     \
    B_GLLJ(NXT, (KT)+1, 0); B_GLLJ(NXT, (KT)+1, 1);              \
    DSREAD_A(CUR, c0, 4);                                        \
    BARLG(); MF16(4); ENDBAR();                                  \
    /* P2 */                                                     \
    B_GLLJ(NXT, (KT)+1, 2); B_GLLJ(NXT, (KT)+1, 3);              \
    DSREAD_B(CUR, c1); DSREAD_A(CUR, c1, 0);                     \
    BARLG(); MF16(0); ENDBAR();                                  \
    /* P3 */                                                     \
    asm volatile("s_waitcnt vmcnt(4)" ::: "memory");             \
    A_WRITE(NXT);                                                \
    DSREAD_A(CUR, c1, 4);                                        \
    BARLG(); MF16(4);                                            \
    asm volatile("s_waitcnt vmcnt(0)" ::: "memory");             \
    ENDBAR();                                                    \
  } while (0)

  // ---- prologue: stage tile 0 into buf 0 ----
  A_ISSUE(0);
  B_GLLJ(0, 0, 0); B_GLLJ(0, 0, 1); B_GLLJ(0, 0, 2); B_GLLJ(0, 0, 3);
  asm volatile("s_waitcnt vmcnt(4)" ::: "memory");
  A_WRITE(0);
  asm volatile("s_waitcnt vmcnt(0) lgkmcnt(0)" ::: "memory");
  __builtin_amdgcn_s_barrier();

  // ---- main: tiles 0..30 staged-computed, buffers alternate ----
  for (int kb = 0; kb < 30; kb += 2) {
    TILE(kb,     0, 1);
    TILE(kb + 1, 1, 0);
  }
  TILE(30, 0, 1);

  // ---- tail: tile 31 from buf 1, no staging/barriers ----
#pragma unroll
  for (int ks = 0; ks < 2; ks++) {
    const int cks = ks ? c1 : c0;
    DSREAD_B(1, cks);
    DSREAD_A(1, cks, 0);
    MF16(0);
    DSREAD_A(1, cks, 4);
    MF16(4);
  }

  // epilogue: scores partial = sum_cols tanh(acc + b_enc + att2) * W_full
  float be[4], wf[4];
  int colv[4];
#pragma unroll
  for (int ni = 0; ni < 4; ni++) {
    colv[ni] = bn0 + wc*64 + ni*16 + l15;
    be[ni] = b_enc[colv[ni]];
    wf[ni] = W_full[colv[ni]];
  }
#pragma unroll
  for (int mi = 0; mi < 8; mi++) {
#pragma unroll
    for (int e = 0; e < 4; e++) {
      const int row_l = wr*128 + mi*16 + hi*4 + e;
      const unsigned gr = (unsigned)(bm0 + row_l);
      const unsigned b  = gr / 196u;
      float s = 0.f;
#pragma unroll
      for (int ni = 0; ni < 4; ni++) {
        const float v = acc[mi][ni][e] + be[ni] + att2[(size_t)b*ADIM + colv[ni]];
        s += tanhf(v) * wf[ni];
      }
      s += __shfl_xor(s, 1); s += __shfl_xor(s, 2);
      s += __shfl_xor(s, 4); s += __shfl_xor(s, 8);
      if (l15 == 0) atomicAdd(&sc[row_l], s);
    }
  }
  __syncthreads();
  if (t < BM) atomicAdd(&scores[bm0 + t], sc[t]);
}

// ---------------- K2: softmax over P per batch (in place) -------------------
__global__ void k_softmax(float* __restrict__ sa) {   // [512][196]
  __shared__ float red[256];
  const int b = blockIdx.x, t = threadIdx.x;
  const float v = (t < PIX) ? sa[(size_t)b*PIX + t] : -1e30f;
  red[t] = v; __syncthreads();
  for (int s2 = 128; s2 > 0; s2 >>= 1) {
    if (t < s2) red[t] = fmaxf(red[t], red[t + s2]);
    __syncthreads();
  }
  const float m = red[0]; __syncthreads();
  const float e = (t < PIX) ? __expf(v - m) : 0.f;
  red[t] = e; __syncthreads();
  for (int s2 = 128; s2 > 0; s2 >>= 1) {
    if (t < s2) red[t] += red[t + s2];
    __syncthreads();
  }
  const float inv = 1.f / red[0];
  if (t < PIX) sa[(size_t)b*PIX + t] = e * inv;
}

// ---------------- K3: context = sum_p alpha[p] * enc[b][p][:] ---------------
__global__ __launch_bounds__(512) void k_context(
    const float* __restrict__ enc, const float* __restrict__ alpha,
    float* __restrict__ ctx) {
  __shared__ float al[PIX];
  const int b = blockIdx.x, t = threadIdx.x;
  if (t < PIX) al[t] = alpha[(size_t)b*PIX + t];
  __syncthreads();
  const float4* e4 = (const float4*)(enc + (size_t)b * PIX * EDIM);
  float4 acc = {0.f, 0.f, 0.f, 0.f};
#pragma unroll 4
  for (int p = 0; p < PIX; p++) {
    const float4 v = e4[(size_t)p * (EDIM/4) + t];
    const float a = al[p];
    acc.x += v.x * a; acc.y += v.y * a; acc.z += v.z * a; acc.w += v.w * a;
  }
  ((float4*)(ctx + (size_t)b * EDIM))[t] = acc;
}

// ---------------------------------------------------------------------------
extern "C" void kernel_launch(void* const* d_in, const int* in_sizes, int n_in,
                              void* d_out, int out_size, void* d_ws, size_t ws_size,
                              hipStream_t stream) {
  (void)in_sizes; (void)n_in; (void)out_size; (void)ws_size;
  const float* enc   = (const float*)d_in[0];
  const float* hid   = (const float*)d_in[1];
  const float* Wenc  = (const float*)d_in[2];
  const float* benc  = (const float*)d_in[3];
  const float* Wdec  = (const float*)d_in[4];
  const float* bdec  = (const float*)d_in[5];
  const float* Wfull = (const float*)d_in[6];
  // d_in[7] = b_full: softmax-invariant, unused.

  unsigned short* Bt = (unsigned short*)d_ws;                       // 2 MB
  float* att2 = (float*)((char*)d_ws + (size_t)ADIM * EDIM * 2);    // 1 MB
  float* ctx   = (float*)d_out;
  float* alpha = (float*)d_out + (size_t)BATCH * EDIM;              // scores live here

  hipMemsetAsync(alpha, 0, (size_t)MROWS * sizeof(float), stream);
  k_transpose_wenc<<<dim3(64, 16), dim3(32, 8), 0, stream>>>(Wenc, Bt);
  k_att2<<<BATCH, 256, 0, stream>>>(hid, Wdec, bdec, att2);
  k_gemm_scores<<<784, 512, 0, stream>>>(enc, Bt, benc, att2, Wfull, alpha);
  k_softmax<<<BATCH, 256, 0, stream>>>(alpha);
  k_context<<<BATCH, 512, 0, stream>>>(enc, alpha, ctx);
}

// Round 9
// 667.325 us; speedup vs baseline: 1.1005x; 1.1005x over previous
//
#include <hip/hip_runtime.h>
#include <hip/hip_bf16.h>
#include <stdint.h>

#define BATCH 512
#define PIX   196
#define EDIM  2048
#define DDIM  512
#define ADIM  512
#define MROWS (BATCH*PIX)   // 100352 = 392*256

#define BM 256
#define BN 256
#define BK 32
#define NT (EDIM/BK)        // 64

typedef __attribute__((ext_vector_type(8))) short bf16x8;
typedef __attribute__((ext_vector_type(8))) float f32x8;
typedef __attribute__((ext_vector_type(8))) __bf16 bf16v8;
typedef __attribute__((ext_vector_type(4))) float f32x4;

#define GLL16(g, lptr) __builtin_amdgcn_global_load_lds( \
    (const __attribute__((address_space(1))) void*)(g),  \
    (__attribute__((address_space(3))) void*)(lptr), 16, 0, 0)

static __device__ __forceinline__ unsigned short f2bf(float f) {
  union { float f; uint32_t u; } v; v.f = f;
  uint32_t u = v.u;
  return (unsigned short)((u + 0x7FFFu + ((u >> 16) & 1u)) >> 16);  // RNE
}

// fp32x8 -> bf16x8 via compiler-selected v_cvt_pk_bf16_f32 (RNE)
static __device__ __forceinline__ bf16x8 cvt8(float4 a, float4 b) {
  f32x8 v = {a.x, a.y, a.z, a.w, b.x, b.y, b.z, b.w};
  bf16v8 c = __builtin_convertvector(v, bf16v8);
  bf16x8 r;
  __builtin_memcpy(&r, &c, 16);
  return r;
}

// ---------------- K0a: W_enc [2048][512] f32 -> Bt [512][2048] bf16 ----------
__global__ void k_transpose_wenc(const float* __restrict__ W,
                                 unsigned short* __restrict__ Bt) {
  __shared__ float tile[32][33];
  const int kt = blockIdx.x;            // 64 tiles over K
  const int nt = blockIdx.y;            // 16 tiles over N
  const int tx = threadIdx.x, ty = threadIdx.y;   // 32 x 8
#pragma unroll
  for (int j = 0; j < 4; j++)
    tile[ty + 8*j][tx] = W[(size_t)(kt*32 + ty + 8*j)*ADIM + nt*32 + tx];
  __syncthreads();
#pragma unroll
  for (int j = 0; j < 4; j++)
    Bt[(size_t)(nt*32 + ty + 8*j)*EDIM + kt*32 + tx] = f2bf(tile[tx][ty + 8*j]);
}

// ---------------- K0b: att2 = hidden @ W_dec + b_dec ------------------------
__global__ void k_att2(const float* __restrict__ H, const float* __restrict__ Wd,
                       const float* __restrict__ bd, float* __restrict__ att2) {
  __shared__ float h[DDIM];
  const int b = blockIdx.x;
  const int t = threadIdx.x;            // 256
  h[t]       = H[(size_t)b*DDIM + t];
  h[t + 256] = H[(size_t)b*DDIM + t + 256];
  __syncthreads();
  float a0 = 0.f, a1 = 0.f;
#pragma unroll 8
  for (int k = 0; k < DDIM; k++) {
    const float hv = h[k];
    a0 += hv * Wd[(size_t)k*ADIM + t];
    a1 += hv * Wd[(size_t)k*ADIM + t + 256];
  }
  att2[(size_t)b*ADIM + t]       = a0 + bd[t];
  att2[(size_t)b*ADIM + t + 256] = a1 + bd[t + 256];
}

// ---------------- K1: fused att1-GEMM + tanh + scores(partial) --------------
// 256x256 tile, BK=32, 512 threads (8 waves 2Mx4N, 128x64 out per wave).
// A fp32 + B bf16 both staged via coalesced global_load_lds (8 lanes/row,
// XOR-pre-swizzled source chunks); A cvt to bf16 at fragment-read (cvt_pk).
// THREE LDS buffers (144 KB) -> true counted vmcnt: stage tile t+2 during
// tile t (A at P0, B at P1), wait vmcnt(6) at tile end => tile t+1 drained,
// t+2's 6 loads always in flight. 2 phases/tile, 16 MFMA each.
__global__ __launch_bounds__(512) void k_gemm_scores(
    const float* __restrict__ enc,          // [M][2048] f32
    const unsigned short* __restrict__ Bt,  // [512][2048] bf16
    const float* __restrict__ b_enc,        // [512]
    const float* __restrict__ att2,         // [B][512]
    const float* __restrict__ W_full,       // [512]
    float* __restrict__ scores)             // [M] (pre-zeroed, atomicAdd)
{
  __shared__ __align__(16) char ldsbuf[3*49152];   // 3 x (32KB A + 16KB B)
  __shared__ float sc[BM];
  char* ldsA = ldsbuf;             // bufA[i] at i*32768
  char* ldsB = ldsbuf + 98304;     // bufB[i] at i*16384

  const int t   = threadIdx.x;          // 0..511
  const int l   = t & 63;
  const int wid = t >> 6;               // 0..7
  const int wr  = wid >> 2;             // 0..1 (M)
  const int wc  = wid & 3;              // 0..3 (N)

  // XCD swizzle (nwg=784=8*98), n-minor: the 2 N-tiles of one M-tile run
  // consecutively on one XCD -> A-tile L2-resident across both.
  const int orig = blockIdx.x;
  const int tile = (orig & 7) * 98 + (orig >> 3);
  const int bm0 = (tile >> 1) * BM;
  const int bn0 = (tile & 1) * BN;

  if (t < BM) sc[t] = 0.f;

  // ---- A staging: 32KB/tile = 2048 chunks; idx=j*512+t -> row=idx>>3,
  //      slot c=idx&7; source chunk = c ^ (row&7) (read-side XOR matches) ----
  const float* srcA[4];
#pragma unroll
  for (int j = 0; j < 4; j++) {
    const int idx = j*512 + t;
    const int row = idx >> 3, c = idx & 7;
    srcA[j] = enc + (size_t)(bm0 + row) * EDIM + (c ^ (row & 7)) * 4;
  }
  // ---- B staging: 16KB/tile = 1024 chunks; idx=j*512+t -> row=idx>>2,
  //      slot c=idx&3; source chunk = c ^ (row&3) ----
  const unsigned short* srcB[2];
#pragma unroll
  for (int j = 0; j < 2; j++) {
    const int idx = j*512 + t;
    const int row = idx >> 2, c = idx & 3;
    srcB[j] = Bt + (size_t)(bn0 + row) * EDIM + (c ^ (row & 3)) * 8;
  }
  const int dstb = wid * 1024;          // + j*8192 ; lane*16 implicit

  // ---- fragment read addresses ----
  const int l15 = l & 15, hi = l >> 4;
  const int sw7 = l15 & 7, sw3 = l15 & 3;
  const int addrA0 = (wr*128 + l15)*128 + (((2*hi)    ) ^ sw7)*16;
  const int addrA1 = (wr*128 + l15)*128 + (((2*hi) + 1) ^ sw7)*16;
  const int addrB  = (wc*64  + l15)*64  + (hi ^ sw3)*16;

  bf16x8 af[4], bfr[4];
  f32x4 acc[8][4] = {};

#define A_GLL(WB, KT) do {                                       \
    _Pragma("unroll")                                            \
    for (int j = 0; j < 4; j++)                                  \
      GLL16(srcA[j] + (size_t)(KT)*BK,                           \
            ldsA + (WB)*32768 + j*8192 + dstb);                  \
  } while (0)

#define B_GLL(WB, KT) do {                                       \
    _Pragma("unroll")                                            \
    for (int j = 0; j < 2; j++)                                  \
      GLL16(srcB[j] + (size_t)(KT)*BK,                           \
            ldsB + (WB)*16384 + j*8192 + dstb);                  \
  } while (0)

#define DSREAD_A(BUF, MOFF) do {                                 \
    _Pragma("unroll")                                            \
    for (int mi = 0; mi < 4; mi++) {                             \
      const float4 fa = *(const float4*)(ldsA + (BUF)*32768 + (mi+(MOFF))*2048 + addrA0); \
      const float4 fb = *(const float4*)(ldsA + (BUF)*32768 + (mi+(MOFF))*2048 + addrA1); \
      af[mi] = cvt8(fa, fb);                                     \
    }                                                            \
  } while (0)

#define DSREAD_B(BUF) do {                                       \
    _Pragma("unroll")                                            \
    for (int ni = 0; ni < 4; ni++)                               \
      bfr[ni] = *(const bf16x8*)(ldsB + (BUF)*16384 + ni*1024 + addrB); \
  } while (0)

#define BARLG()                                                  \
    __builtin_amdgcn_s_barrier();                                \
    asm volatile("s_waitcnt lgkmcnt(0)" ::: "memory");           \
    __builtin_amdgcn_sched_barrier(0);                           \
    __builtin_amdgcn_s_setprio(1)

#define ENDBAR()                                                 \
    __builtin_amdgcn_s_setprio(0);                               \
    __builtin_amdgcn_s_barrier()

#define MF16(MOFF) do {                                          \
    _Pragma("unroll")                                            \
    for (int mi = 0; mi < 4; mi++)                               \
      _Pragma("unroll")                                          \
      for (int ni = 0; ni < 4; ni++)                             \
        acc[mi+(MOFF)][ni] = __builtin_amdgcn_mfma_f32_16x16x32_bf16( \
            af[mi], bfr[ni], acc[mi+(MOFF)][ni], 0, 0, 0);       \
  } while (0)

  // One K-tile = 2 phases. Reads BUF; stages tile T+2 into WBUF=(T+2)%3.
  // WVM: -1 none, 6 steady (t+1 drained, t+2 flies), 0 tail.
#define TILE(T, BUF, WBUF, DO_STAGE, WVM) do {                   \
    /* P0 */                                                     \
    if (DO_STAGE) A_GLL(WBUF, (T)+2);                            \
    DSREAD_B(BUF); DSREAD_A(BUF, 0);                             \
    BARLG(); MF16(0); ENDBAR();                                  \
    /* P1 */                                                     \
    if (DO_STAGE) B_GLL(WBUF, (T)+2);                            \
    DSREAD_A(BUF, 4);                                            \
    BARLG(); MF16(4);                                            \
    if ((WVM) == 6)      asm volatile("s_waitcnt vmcnt(6)" ::: "memory"); \
    else if ((WVM) == 0) asm volatile("s_waitcnt vmcnt(0)" ::: "memory"); \
    ENDBAR();                                                    \
  } while (0)

  // ---- prologue: stage tiles 0,1; wait tile 0 (6 of 12 remain) ----
  A_GLL(0, 0); B_GLL(0, 0);
  A_GLL(1, 1); B_GLL(1, 1);
  asm volatile("s_waitcnt vmcnt(6)" ::: "memory");
  __builtin_amdgcn_s_barrier();

  // ---- main: tiles 0..59 (20 x unroll-3) ----
  for (int kb = 0; kb < 60; kb += 3) {
    TILE(kb,     0, 2, true, 6);
    TILE(kb + 1, 1, 0, true, 6);
    TILE(kb + 2, 2, 1, true, 6);
  }
  TILE(60, 0, 2, true, 6);    // stages tile 62
  TILE(61, 1, 0, true, 6);    // stages tile 63
  TILE(62, 2, 2, false, 0);   // nothing left to stage; drain tile 63
  // ---- tail: tile 63 from buf 0, no barriers needed ----
  DSREAD_B(0); DSREAD_A(0, 0); MF16(0);
  DSREAD_A(0, 4); MF16(4);

  // epilogue: scores partial = sum_cols tanh(acc + b_enc + att2) * W_full
  float be[4], wf[4];
  int colv[4];
#pragma unroll
  for (int ni = 0; ni < 4; ni++) {
    colv[ni] = bn0 + wc*64 + ni*16 + l15;
    be[ni] = b_enc[colv[ni]];
    wf[ni] = W_full[colv[ni]];
  }
#pragma unroll
  for (int mi = 0; mi < 8; mi++) {
#pragma unroll
    for (int e = 0; e < 4; e++) {
      const int row_l = wr*128 + mi*16 + hi*4 + e;
      const unsigned gr = (unsigned)(bm0 + row_l);
      const unsigned b  = gr / 196u;
      float s = 0.f;
#pragma unroll
      for (int ni = 0; ni < 4; ni++) {
        const float v = acc[mi][ni][e] + be[ni] + att2[(size_t)b*ADIM + colv[ni]];
        s += tanhf(v) * wf[ni];
      }
      s += __shfl_xor(s, 1); s += __shfl_xor(s, 2);
      s += __shfl_xor(s, 4); s += __shfl_xor(s, 8);
      if (l15 == 0) atomicAdd(&sc[row_l], s);
    }
  }
  __syncthreads();
  if (t < BM) atomicAdd(&scores[bm0 + t], sc[t]);
}

// ---------------- K2: softmax over P per batch (in place) -------------------
__global__ void k_softmax(float* __restrict__ sa) {   // [512][196]
  __shared__ float red[256];
  const int b = blockIdx.x, t = threadIdx.x;
  const float v = (t < PIX) ? sa[(size_t)b*PIX + t] : -1e30f;
  red[t] = v; __syncthreads();
  for (int s2 = 128; s2 > 0; s2 >>= 1) {
    if (t < s2) red[t] = fmaxf(red[t], red[t + s2]);
    __syncthreads();
  }
  const float m = red[0]; __syncthreads();
  const float e = (t < PIX) ? __expf(v - m) : 0.f;
  red[t] = e; __syncthreads();
  for (int s2 = 128; s2 > 0; s2 >>= 1) {
    if (t < s2) red[t] += red[t + s2];
    __syncthreads();
  }
  const float inv = 1.f / red[0];
  if (t < PIX) sa[(size_t)b*PIX + t] = e * inv;
}

// ---------------- K3: context = sum_p alpha[p] * enc[b][p][:] ---------------
__global__ __launch_bounds__(512) void k_context(
    const float* __restrict__ enc, const float* __restrict__ alpha,
    float* __restrict__ ctx) {
  __shared__ float al[PIX];
  const int b = blockIdx.x, t = threadIdx.x;
  if (t < PIX) al[t] = alpha[(size_t)b*PIX + t];
  __syncthreads();
  const float4* e4 = (const float4*)(enc + (size_t)b * PIX * EDIM);
  float4 acc = {0.f, 0.f, 0.f, 0.f};
#pragma unroll 4
  for (int p = 0; p < PIX; p++) {
    const float4 v = e4[(size_t)p * (EDIM/4) + t];
    const float a = al[p];
    acc.x += v.x * a; acc.y += v.y * a; acc.z += v.z * a; acc.w += v.w * a;
  }
  ((float4*)(ctx + (size_t)b * EDIM))[t] = acc;
}

// ---------------------------------------------------------------------------
extern "C" void kernel_launch(void* const* d_in, const int* in_sizes, int n_in,
                              void* d_out, int out_size, void* d_ws, size_t ws_size,
                              hipStream_t stream) {
  (void)in_sizes; (void)n_in; (void)out_size; (void)ws_size;
  const float* enc   = (const float*)d_in[0];
  const float* hid   = (const float*)d_in[1];
  const float* Wenc  = (const float*)d_in[2];
  const float* benc  = (const float*)d_in[3];
  const float* Wdec  = (const float*)d_in[4];
  const float* bdec  = (const float*)d_in[5];
  const float* Wfull = (const float*)d_in[6];
  // d_in[7] = b_full: softmax-invariant, unused.

  unsigned short* Bt = (unsigned short*)d_ws;                       // 2 MB
  float* att2 = (float*)((char*)d_ws + (size_t)ADIM * EDIM * 2);    // 1 MB
  float* ctx   = (float*)d_out;
  float* alpha = (float*)d_out + (size_t)BATCH * EDIM;              // scores live here

  hipMemsetAsync(alpha, 0, (size_t)MROWS * sizeof(float), stream);
  k_transpose_wenc<<<dim3(64, 16), dim3(32, 8), 0, stream>>>(Wenc, Bt);
  k_att2<<<BATCH, 256, 0, stream>>>(hid, Wdec, bdec, att2);
  k_gemm_scores<<<784, 512, 0, stream>>>(enc, Bt, benc, att2, Wfull, alpha);
  k_softmax<<<BATCH, 256, 0, stream>>>(alpha);
  k_context<<<BATCH, 512, 0, stream>>>(enc, alpha, ctx);
}